// Round 1
// baseline (2121.689 us; speedup 1.0000x reference)
//
#include <hip/hip_runtime.h>

// ChemicalLLM: x_{t+1} = norm(relu(x + a*einsum(W,x,x))), then big decode GEMM.
// Design:
//  - recur_kernel: 8 blocks (1 per batch, 1 CU each). W quantized to int8 and
//    held REGISTER-RESIDENT (128 VGPRs/lane * 8 waves = 256 KB). Per step:
//    sdot4 chains (i8) for the inner i-contraction, exact-f32 outer j factor,
//    f32 epilogue (relu/normalize) on wave0. Emb rows prefetched 1 step ahead.
//  - decode_kernel: bf16 MFMA 16x16x32, split-bf16 (hi+lo) 3-pass for ~f32
//    accuracy. Output write-bound (~1.05 GB).
//  - prep kernels: W absmax -> int8 pack; Wd -> bf16 hi/lo split.

typedef unsigned int u32;
typedef unsigned short u16;
typedef __attribute__((ext_vector_type(8))) short short8;
typedef __attribute__((ext_vector_type(4))) float f32x4;

#define DECAY_ 0.1f
#define ALPHA_ 0.2f
#define EPS_ 1e-8f
#define B_ 8
#define S_ 1024
#define N_ 64
#define V_ 32000

// ---------- bf16 helpers (manual, RNE) ----------
static __device__ __forceinline__ u16 f2bf(float f) {
  u32 u = __float_as_uint(f);
  u32 r = (u + 0x7fffu + ((u >> 16) & 1u)) >> 16;
  return (u16)r;
}
static __device__ __forceinline__ float bf2f(u16 h) {
  return __uint_as_float(((u32)h) << 16);
}

// ---------- int8 dot4 ----------
#if defined(__has_builtin)
#if __has_builtin(__builtin_amdgcn_sdot4)
#define HAVE_SDOT4 1
#endif
#endif
static __device__ __forceinline__ int dot4(int a, int b, int c) {
#ifdef HAVE_SDOT4
  return __builtin_amdgcn_sdot4(a, b, c, false);
#else
  int s = c;
  s += (int)(signed char)(a) * (int)(signed char)(b);
  s += (int)(signed char)(a >> 8) * (int)(signed char)(b >> 8);
  s += (int)(signed char)(a >> 16) * (int)(signed char)(b >> 16);
  s += (int)(a >> 24) * (int)(b >> 24);
  return s;
#endif
}

static __device__ __forceinline__ float wave_max64(float v) {
#pragma unroll
  for (int m = 1; m < 64; m <<= 1) v = fmaxf(v, __shfl_xor(v, m, 64));
  return v;
}
static __device__ __forceinline__ float wave_sum64(float v) {
#pragma unroll
  for (int m = 1; m < 64; m <<= 1) v += __shfl_xor(v, m, 64);
  return v;
}

// ---------- prep: |W| max ----------
__global__ void wmax_kernel(const float* __restrict__ W, u32* __restrict__ out) {
  int gid = blockIdx.x * blockDim.x + threadIdx.x;
  int stride = gridDim.x * blockDim.x;
  float m = 0.0f;
  for (int i = gid; i < N_ * N_ * N_; i += stride) m = fmaxf(m, fabsf(W[i]));
  m = wave_max64(m);
  if ((threadIdx.x & 63) == 0) atomicMax(out, __float_as_uint(m));  // f>=0: bits monotone
}

// ---------- prep: quantize+pack W ----------
// Wq dword idx = (j*16 + q)*64 + k packs W[4q+e][j][k] for e=0..3 (i packed along bytes)
__global__ void quantw_kernel(const float* __restrict__ W, const u32* __restrict__ wmaxb,
                              u32* __restrict__ Wq) {
  int idx = blockIdx.x * blockDim.x + threadIdx.x;  // 65536 threads
  float s = 127.0f / fmaxf(__uint_as_float(wmaxb[0]), 1e-30f);
  int j = idx >> 10;
  int q = (idx >> 6) & 15;
  int k = idx & 63;
  u32 pk = 0;
#pragma unroll
  for (int e = 0; e < 4; ++e) {
    float v = W[(((4 * q + e) * N_) + j) * N_ + k];
    int qi = (int)rintf(v * s);
    qi = qi > 127 ? 127 : (qi < -127 ? -127 : qi);
    pk |= ((u32)qi & 0xffu) << (8 * e);
  }
  Wq[idx] = pk;
}

// ---------- prep: Wd -> bf16 hi/lo split ----------
__global__ void wdsplit_kernel(const float* __restrict__ Wd, u16* __restrict__ hi,
                               u16* __restrict__ lo) {
  int idx = blockIdx.x * blockDim.x + threadIdx.x;  // 2048000
  float v = Wd[idx];
  u16 hb = f2bf(v);
  hi[idx] = hb;
  lo[idx] = f2bf(v - bf2f(hb));
}

// ---------- the serial recurrence: 1 block per batch ----------
__global__ __launch_bounds__(512, 2) void recur_kernel(
    const int* __restrict__ ids, const float* __restrict__ emb,
    const u32* __restrict__ Wq, const u32* __restrict__ wmaxb,
    u16* __restrict__ hs_hi, u16* __restrict__ hs_lo, float* __restrict__ outHT) {
  const int b = blockIdx.x;
  const int tid = threadIdx.x;
  const int lane = tid & 63;  // = k index in dot phase
  const int w = tid >> 6;     // wave 0..7, owns j in [8w, 8w+8)

  __shared__ float xf[N_];    // current x (f32, exact)
  __shared__ u32 xq[16];      // current x quantized u8, packed 4/dword along i
  __shared__ float part[8 * 64];
  __shared__ float smulS;     // (mx/127)*(wmax/127)

  const float sWq = __uint_as_float(wmaxb[0]) * (1.0f / 127.0f);

  // W register-resident: lane holds Wq[(j=8w+r, iblock=q), k=lane] for r<8,q<16
  u32 wreg[128];
#pragma unroll
  for (int r = 0; r < 8; ++r) {
#pragma unroll
    for (int q = 0; q < 16; ++q)
      wreg[r * 16 + q] = Wq[(((8 * w + r) * 16 + q) << 6) + lane];
  }

  float xk = 0.0f;       // wave0: this lane's current x value
  float pend_emb = 0.0f; // wave0: prefetched emb row value for step t+1
  int pend_id = 0;       // wave0: prefetched ids[t+2]

  if (w == 0) {
    int id0 = ids[b * S_];
    float e0 = emb[(size_t)id0 * N_ + lane];
    xk = fmaxf(e0, 0.0f);  // x_0 = relu(emb row), h_0 = 0
    float mx = wave_max64(xk);
    float inv = 127.0f / fmaxf(mx, 1e-30f);
    float u = xk * inv;
    xf[lane] = xk;
    if (lane == 0) smulS = (mx * (1.0f / 127.0f)) * sWq;
    float u0 = __shfl(u, (lane & 15) * 4 + 0, 64);
    float u1 = __shfl(u, (lane & 15) * 4 + 1, 64);
    float u2 = __shfl(u, (lane & 15) * 4 + 2, 64);
    float u3 = __shfl(u, (lane & 15) * 4 + 3, 64);
    if (lane < 16) {
      u32 pk = (u32)(int)rintf(u0) | ((u32)(int)rintf(u1) << 8) |
               ((u32)(int)rintf(u2) << 16) | ((u32)(int)rintf(u3) << 24);
      xq[lane] = pk;
    }
    int id1 = ids[b * S_ + 1];
    pend_emb = emb[(size_t)id1 * N_ + lane];
    pend_id = ids[b * S_ + 2];
  }
  __syncthreads();

  for (int t = 0; t < S_; ++t) {
    // ---- dot phase (all 8 waves): partial iact over this wave's 8 j's ----
    u32 xr[16];
#pragma unroll
    for (int q = 0; q < 16; ++q) xr[q] = xq[q];
    int acc[8];
#pragma unroll
    for (int r = 0; r < 8; ++r) {
      int a = 0;
#pragma unroll
      for (int q = 0; q < 16; ++q) a = dot4((int)xr[q], (int)wreg[r * 16 + q], a);
      acc[r] = a;
    }
    float pf = 0.0f;
#pragma unroll
    for (int r = 0; r < 8; ++r) pf += (float)acc[r] * xf[8 * w + r];  // exact-f32 x_j
    pf *= smulS;
    part[(w << 6) + lane] = pf;
    __syncthreads();

    // ---- epilogue (wave0 only) ----
    if (w == 0) {
      float iact = 0.0f;
#pragma unroll
      for (int q = 0; q < 8; ++q) iact += part[(q << 6) + lane];
      float xact = fmaxf(xk + ALPHA_ * iact, 0.0f);
      float Ssum = wave_sum64(xact);
      float h = xact / (Ssum + EPS_);

      int m = b * S_ + t;
      u16 hb = f2bf(h);
      float hf = bf2f(hb);
      u16 lb = f2bf(h - hf);
      hs_hi[(size_t)m * N_ + lane] = hb;
      hs_lo[(size_t)m * N_ + lane] = lb;
      if (t == S_ - 1) outHT[b * N_ + lane] = h;

      // next state
      float wn = fmaxf(pend_emb, 0.0f);
      float xn = (1.0f - DECAY_) * h + wn;
      int idn = pend_id;
      if (t + 2 < S_) pend_emb = emb[(size_t)idn * N_ + lane];  // row for t+2
      pend_id = ids[b * S_ + ((t + 3 < S_) ? (t + 3) : (S_ - 1))];

      float mx = wave_max64(xn);
      float inv = 127.0f / fmaxf(mx, 1e-30f);
      float u = xn * inv;
      xf[lane] = xn;
      if (lane == 0) smulS = (mx * (1.0f / 127.0f)) * sWq;
      float u0 = __shfl(u, (lane & 15) * 4 + 0, 64);
      float u1 = __shfl(u, (lane & 15) * 4 + 1, 64);
      float u2 = __shfl(u, (lane & 15) * 4 + 2, 64);
      float u3 = __shfl(u, (lane & 15) * 4 + 3, 64);
      if (lane < 16) {
        u32 pk = (u32)(int)rintf(u0) | ((u32)(int)rintf(u1) << 8) |
                 ((u32)(int)rintf(u2) << 16) | ((u32)(int)rintf(u3) << 24);
        xq[lane] = pk;
      }
      xk = xn;
    }
    __syncthreads();
  }
}

// ---------- decode: logits = hs @ Wd^T + bd, split-bf16 3-pass MFMA ----------
__global__ __launch_bounds__(256) void decode_kernel(
    const u16* __restrict__ hs_hi, const u16* __restrict__ hs_lo,
    const u16* __restrict__ wd_hi, const u16* __restrict__ wd_lo,
    const float* __restrict__ bd, float* __restrict__ out) {
  const int lane = threadIdx.x & 63;
  const int w = threadIdx.x >> 6;          // 4 waves, each 16 M-rows
  const int n0 = blockIdx.x * 64;          // V block
  const int m0 = blockIdx.y * 64 + w * 16; // M rows for this wave
  const int row = m0 + (lane & 15);
  const int kg = (lane >> 4) * 8;

  // A fragments: row = lane&15, k = (lane>>4)*8 + e (+32 for kstep 1)
  short8 ah0 = *(const short8*)(hs_hi + (size_t)row * N_ + kg);
  short8 ah1 = *(const short8*)(hs_hi + (size_t)row * N_ + 32 + kg);
  short8 al0 = *(const short8*)(hs_lo + (size_t)row * N_ + kg);
  short8 al1 = *(const short8*)(hs_lo + (size_t)row * N_ + 32 + kg);

#pragma unroll
  for (int nt = 0; nt < 4; ++nt) {
    int v = n0 + nt * 16 + (lane & 15);
    short8 bh0 = *(const short8*)(wd_hi + (size_t)v * N_ + kg);
    short8 bh1 = *(const short8*)(wd_hi + (size_t)v * N_ + 32 + kg);
    short8 bl0 = *(const short8*)(wd_lo + (size_t)v * N_ + kg);
    short8 bl1 = *(const short8*)(wd_lo + (size_t)v * N_ + 32 + kg);
    float bdv = bd[v];
    f32x4 acc = {bdv, bdv, bdv, bdv};
    acc = __builtin_amdgcn_mfma_f32_16x16x32_bf16(ah0, bh0, acc, 0, 0, 0);
    acc = __builtin_amdgcn_mfma_f32_16x16x32_bf16(ah1, bh1, acc, 0, 0, 0);
    acc = __builtin_amdgcn_mfma_f32_16x16x32_bf16(ah0, bl0, acc, 0, 0, 0);
    acc = __builtin_amdgcn_mfma_f32_16x16x32_bf16(ah1, bl1, acc, 0, 0, 0);
    acc = __builtin_amdgcn_mfma_f32_16x16x32_bf16(al0, bh0, acc, 0, 0, 0);
    acc = __builtin_amdgcn_mfma_f32_16x16x32_bf16(al1, bh1, acc, 0, 0, 0);
#pragma unroll
    for (int i = 0; i < 4; ++i) {
      int r = m0 + (lane >> 4) * 4 + i;
      out[(size_t)r * V_ + v] = acc[i];
    }
  }
}

// ---------- launch ----------
extern "C" void kernel_launch(void* const* d_in, const int* in_sizes, int n_in,
                              void* d_out, int out_size, void* d_ws, size_t ws_size,
                              hipStream_t stream) {
  const int* ids = (const int*)d_in[0];
  const float* emb = (const float*)d_in[1];
  const float* W = (const float*)d_in[2];
  const float* Wd = (const float*)d_in[3];
  const float* bd = (const float*)d_in[4];
  float* out = (float*)d_out;
  char* ws = (char*)d_ws;

  // ws layout (bytes): [Wq 262144][wmax 64][hs_hi 1MiB][hs_lo 1MiB][wd_hi 4096000][wd_lo 4096000]
  u32* Wq = (u32*)(ws);
  u32* wmax = (u32*)(ws + 262144);
  u16* hs_hi = (u16*)(ws + 262208);
  u16* hs_lo = (u16*)(ws + 1310784);
  u16* wd_hi = (u16*)(ws + 2359360);
  u16* wd_lo = (u16*)(ws + 6455360);

  hipMemsetAsync(wmax, 0, 4, stream);
  hipLaunchKernelGGL(wmax_kernel, dim3(256), dim3(256), 0, stream, W, wmax);
  hipLaunchKernelGGL(quantw_kernel, dim3(256), dim3(256), 0, stream, W, wmax, Wq);
  hipLaunchKernelGGL(wdsplit_kernel, dim3(8000), dim3(256), 0, stream, Wd, wd_hi, wd_lo);
  hipLaunchKernelGGL(recur_kernel, dim3(B_), dim3(512), 0, stream, ids, emb, Wq, wmax,
                     hs_hi, hs_lo, out + (size_t)B_ * S_ * V_);
  hipLaunchKernelGGL(decode_kernel, dim3(V_ / 64, (B_ * S_) / 64), dim3(256), 0, stream,
                     hs_hi, hs_lo, wd_hi, wd_lo, bd, out);

  (void)in_sizes; (void)n_in; (void)out_size; (void)ws_size;
}